// Round 3
// baseline (479.835 us; speedup 1.0000x reference)
//
#include <hip/hip_runtime.h>

#define B_    4
#define CIN_  64
#define COUT_ 64
#define N_    16384
#define K_    8

#define EDGES_PER_B (K_ * N_)            // 131072
#define TOT_EDGES   (B_ * EDGES_PER_B)   // 524288

// ===========================================================================
// PATH A-NEW (~136.5 MiB ws): fused prep + high-occupancy contrib + vec gather
// ===========================================================================

// --- fused: hist + scan + slot-assign + edge-record build, one block/batch -
__global__ __launch_bounds__(1024) void fc_prep(
    const int*   __restrict__ nbh,      // [B, K, N]
    const float* __restrict__ pos,      // [B, 3, N]
    int*         __restrict__ offsets,  // [B, N]
    int*         __restrict__ counts,   // [B, N]
    float4*      __restrict__ rec)      // [B, N, K] {qx,qy,qz, slot}
{
    __shared__ int cnt[N_];      // 64 KiB
    __shared__ int s[1024];      // 4 KiB

    const int b = blockIdx.x;
    const int t = threadIdx.x;

    const int*   nbhb = nbh + (size_t)b * K_ * N_;
    const float* posb = pos + (size_t)b * 3 * N_;
    float4*      recb = rec + (size_t)b * N_ * K_;

    for (int i = t; i < N_; i += 1024) cnt[i] = 0;
    __syncthreads();

    // histogram into LDS
    for (int e = t; e < EDGES_PER_B; e += 1024)
        atomicAdd(&cnt[nbhb[e]], 1);
    __syncthreads();

    // scan: thread owns 16 consecutive bins
    const int base = t * 16;
    int sum = 0;
    #pragma unroll
    for (int q = 0; q < 16; ++q) sum += cnt[base + q];
    s[t] = sum;
    __syncthreads();
    for (int d = 1; d < 1024; d <<= 1) {
        const int v = (t >= d) ? s[t - d] : 0;
        __syncthreads();
        s[t] += v;
        __syncthreads();
    }
    int off = s[t] - sum;               // exclusive base
    #pragma unroll
    for (int q = 0; q < 16; ++q) {
        const int c = cnt[base + q];
        offsets[b * N_ + base + q] = off;
        counts [b * N_ + base + q] = c;
        cnt[base + q] = off;            // becomes cursor
        off += c;
    }
    __syncthreads();

    // slot assignment + edge records (coalesced-ish rec writes, 128 B/point)
    for (int n = t; n < N_; n += 1024) {
        #pragma unroll
        for (int k = 0; k < K_; ++k) {
            const int j    = nbhb[k * N_ + n];
            const int slot = atomicAdd(&cnt[j], 1);
            const float qx = posb[j];
            const float qy = posb[N_ + j];
            const float qz = posb[2 * N_ + j];
            recb[(size_t)n * K_ + k] = make_float4(qx, qy, qz, __int_as_float(slot));
        }
    }
}

// --- phase 1: GEMM for ft/h per source point + per-edge contribution -------
__global__ __launch_bounds__(512, 4) void fc_contribA(
    const float*  __restrict__ feat,    // [B, CIN, N]
    const float*  __restrict__ theta,   // [3, CIN, COUT]
    const float*  __restrict__ wbias,   // [CIN, COUT]
    const float4* __restrict__ rec,     // [B, N, K]
    const float*  __restrict__ pos,     // [B, 3, N]
    float*        __restrict__ contrib) // [B, K*N, COUT]
{
    __shared__ float4 Wl[CIN_ * COUT_];   // 64 KiB
    __shared__ float  Fl[CIN_ * 64];      // 16 KiB

    const int tid  = threadIdx.x;
    const int lane = tid & 63;            // o
    const int w    = tid >> 6;            // wave 0..7

    const int blocks_per_b = N_ / 128;    // 128
    const int b     = blockIdx.x / blocks_per_b;
    const int nbase = (blockIdx.x % blocks_per_b) * 128;

    for (int e = tid; e < CIN_ * COUT_; e += 512) {
        const int i = e >> 6, o = e & 63;
        float4 wv;
        wv.x = theta[0 * CIN_ * COUT_ + i * COUT_ + o];
        wv.y = theta[1 * CIN_ * COUT_ + i * COUT_ + o];
        wv.z = theta[2 * CIN_ * COUT_ + i * COUT_ + o];
        wv.w = wbias[i * COUT_ + o];
        Wl[e] = wv;
    }

    const float*  featb = feat + (size_t)b * CIN_ * N_;
    const float*  posb  = pos  + (size_t)b * 3 * N_;
    const float4* recb  = rec  + (size_t)b * N_ * K_;
    float*        cb    = contrib + ((size_t)b * EDGES_PER_B << 6);

    for (int t = 0; t < 2; ++t) {
        const int n0 = nbase + t * 64;

        __syncthreads();   // Wl ready (t=0) / previous Fl readers done (t=1)
        for (int r = 0; r < 8; ++r) {
            const int i = r * 8 + w;
            Fl[i * 64 + lane] = featb[(size_t)i * N_ + n0 + lane];
        }
        __syncthreads();

        // each wave: 8 points (nn..nn+7)
        const int nn = w * 8;
        float4 acc[8];
        #pragma unroll
        for (int j = 0; j < 8; ++j) acc[j] = make_float4(0.f, 0.f, 0.f, 0.f);

        #pragma unroll 2
        for (int i = 0; i < CIN_; ++i) {
            const float4 wv = Wl[i * 64 + lane];              // conflict-free b128
            const float4 fA = *(const float4*)&Fl[i * 64 + nn];     // broadcast
            const float4 fB = *(const float4*)&Fl[i * 64 + nn + 4]; // broadcast
            const float fs[8] = {fA.x, fA.y, fA.z, fA.w, fB.x, fB.y, fB.z, fB.w};
            #pragma unroll
            for (int j = 0; j < 8; ++j) {
                acc[j].x = fmaf(wv.x, fs[j], acc[j].x);
                acc[j].y = fmaf(wv.y, fs[j], acc[j].y);
                acc[j].z = fmaf(wv.z, fs[j], acc[j].z);
                acc[j].w = fmaf(wv.w, fs[j], acc[j].w);
            }
        }

        #pragma unroll
        for (int j = 0; j < 8; ++j) {
            const int n = n0 + nn + j;
            const float px = posb[0 * N_ + n];
            const float py = posb[1 * N_ + n];
            const float pz = posb[2 * N_ + n];
            float4 a = acc[j];
            a.w = fmaf(-px, a.x, fmaf(-py, a.y, fmaf(-pz, a.z, a.w)));  // h
            #pragma unroll
            for (int k = 0; k < K_; ++k) {
                const float4 r = recb[(size_t)n * K_ + k];    // contiguous bcast
                const int slot = __float_as_int(r.w);
                const float c  = fmaf(r.x, a.x, fmaf(r.y, a.y, fmaf(r.z, a.z, a.w)));
                cb[((size_t)slot << 6) + lane] = c;           // 256 B / wave
            }
        }
    }
}

// --- gather: contiguous cnt*256B range per target, dwordx4 reads -----------
__global__ __launch_bounds__(512) void fc_gatherA(
    const float* __restrict__ contrib,
    const int*   __restrict__ offsets,
    const int*   __restrict__ counts,
    const float* __restrict__ bias,
    float*       __restrict__ out)     // [B, COUT, N]
{
    __shared__ float T[64][65];
    __shared__ float V[64][65];
    const int tid  = threadIdx.x;
    const int lane = tid & 63;
    const int w    = tid >> 6;            // 0..7

    const int tiles_per_b = N_ / 64;      // 256
    const int b  = blockIdx.x / tiles_per_b;
    const int n0 = (blockIdx.x % tiles_per_b) * 64;

    const float*  cb  = contrib + ((size_t)b * EDGES_PER_B << 6);
    const float4* cb4 = (const float4*)cb;

    for (int g = 0; g < 8; ++g) {
        const int jj = w * 8 + g;
        const int j  = n0 + jj;
        const int base = offsets[b * N_ + j];
        const int cnt  = counts[b * N_ + j];

        // vector part: lane l covers row-offset (l>>4), channels 4*(l&15)+c
        const float4* p4 = cb4 + (size_t)base * 16 + lane;
        float4 v = make_float4(0.f, 0.f, 0.f, 0.f);
        const int full = cnt >> 2;          // groups of 4 rows
        int it = 0;
        for (; it + 2 <= full; it += 2) {   // 2 in flight
            const float4 a0 = p4[0];
            const float4 a1 = p4[64];
            v.x += a0.x + a1.x; v.y += a0.y + a1.y;
            v.z += a0.z + a1.z; v.w += a0.w + a1.w;
            p4 += 128;
        }
        if (it < full) {
            const float4 a0 = p4[0];
            v.x += a0.x; v.y += a0.y; v.z += a0.z; v.w += a0.w;
        }
        // reduce the 4 lanes sharing each channel set (l, l+16, l+32, l+48)
        v.x += __shfl_xor(v.x, 16); v.y += __shfl_xor(v.y, 16);
        v.z += __shfl_xor(v.z, 16); v.w += __shfl_xor(v.w, 16);
        v.x += __shfl_xor(v.x, 32); v.y += __shfl_xor(v.y, 32);
        v.z += __shfl_xor(v.z, 32); v.w += __shfl_xor(v.w, 32);

        // scalar tail rows
        float tail = 0.f;
        const float* pt = cb + (((size_t)base + ((size_t)full << 2)) << 6) + lane;
        for (int e = full << 2; e < cnt; ++e) { tail += *pt; pt += 64; }

        T[jj][lane] = tail;
        if (lane < 16) {
            V[jj][4 * lane + 0] = v.x;
            V[jj][4 * lane + 1] = v.y;
            V[jj][4 * lane + 2] = v.z;
            V[jj][4 * lane + 3] = v.w;
        }
    }
    __syncthreads();

    float* outb = out + (size_t)b * COUT_ * N_;
    for (int r = 0; r < 8; ++r) {
        const int o = r * 8 + w;
        outb[(size_t)o * N_ + n0 + lane] = T[lane][o] + V[lane][o] + bias[o];
    }
}

// ===========================================================================
// PATH A-OLD (~131 MiB ws): round-2 verified pipeline (fallback).
// ===========================================================================

__global__ __launch_bounds__(256) void fc_hist(
    const int* __restrict__ nbh,
    int*       __restrict__ counts)
{
    const int gid = blockIdx.x * 256 + threadIdx.x;
    const int b   = gid / EDGES_PER_B;
    const int j   = nbh[gid];
    atomicAdd(&counts[b * N_ + j], 1);
}

__global__ __launch_bounds__(256) void fc_scan(
    const int* __restrict__ counts,
    int*       __restrict__ offsets,
    int*       __restrict__ cursor)
{
    __shared__ int s[256];
    const int b = blockIdx.x;
    const int t = threadIdx.x;
    const int base = b * N_ + t * 64;

    int sum = 0;
    #pragma unroll
    for (int e = 0; e < 64; ++e) sum += counts[base + e];
    s[t] = sum;
    __syncthreads();

    for (int d = 1; d < 256; d <<= 1) {
        const int v = (t >= d) ? s[t - d] : 0;
        __syncthreads();
        s[t] += v;
        __syncthreads();
    }

    int off = s[t] - sum;
    #pragma unroll
    for (int e = 0; e < 64; ++e) {
        const int c = counts[base + e];
        offsets[base + e] = off;
        cursor[base + e]  = off;
        off += c;
    }
}

__global__ __launch_bounds__(256) void fc_fill_slot(
    const int* __restrict__ nbh,
    int*       __restrict__ cursor,
    int*       __restrict__ slotmap)
{
    const int gid = blockIdx.x * 256 + threadIdx.x;
    const int b   = gid / EDGES_PER_B;
    const int j   = nbh[gid];
    slotmap[gid] = atomicAdd(&cursor[b * N_ + j], 1);
}

__global__ __launch_bounds__(256) void fc_contrib(
    const float* __restrict__ feat,
    const float* __restrict__ theta,
    const float* __restrict__ wbias,
    const int*   __restrict__ nbh,
    const int*   __restrict__ slotmap,
    const float* __restrict__ pos,
    float*       __restrict__ contrib)
{
    __shared__ float4 Wl[CIN_ * COUT_];
    __shared__ float  Fl[CIN_ * 64];

    const int tid  = threadIdx.x;
    const int lane = tid & 63;
    const int w    = tid >> 6;

    const int blocks_per_b = N_ / 128;
    const int b     = blockIdx.x / blocks_per_b;
    const int nbase = (blockIdx.x % blocks_per_b) * 128;

    for (int e = tid; e < CIN_ * COUT_; e += 256) {
        const int i = e >> 6, o = e & 63;
        float4 wv;
        wv.x = theta[0 * CIN_ * COUT_ + i * COUT_ + o];
        wv.y = theta[1 * CIN_ * COUT_ + i * COUT_ + o];
        wv.z = theta[2 * CIN_ * COUT_ + i * COUT_ + o];
        wv.w = wbias[i * COUT_ + o];
        Wl[e] = wv;
    }

    const float* featb = feat + (size_t)b * CIN_ * N_;
    const float* posb  = pos  + (size_t)b * 3 * N_;
    const int*   nbhb  = nbh  + (size_t)b * K_ * N_;
    const int*   smb   = slotmap + (size_t)b * EDGES_PER_B;
    float*       cb    = contrib + ((size_t)b * EDGES_PER_B << 6);

    for (int t = 0; t < 2; ++t) {
        const int n0 = nbase + t * 64;

        __syncthreads();
        for (int r = 0; r < 16; ++r) {
            const int i = r * 4 + w;
            Fl[i * 64 + lane] = featb[(size_t)i * N_ + n0 + lane];
        }
        __syncthreads();

        for (int g = 0; g < 4; ++g) {
            const int nn = w * 16 + g * 4;
            float4 acc[4];
            #pragma unroll
            for (int j = 0; j < 4; ++j) acc[j] = make_float4(0.f, 0.f, 0.f, 0.f);

            #pragma unroll 8
            for (int i = 0; i < CIN_; ++i) {
                const float4 wv = Wl[i * 64 + lane];
                const float f0 = Fl[i * 64 + nn + 0];
                const float f1 = Fl[i * 64 + nn + 1];
                const float f2 = Fl[i * 64 + nn + 2];
                const float f3 = Fl[i * 64 + nn + 3];
                acc[0].x = fmaf(wv.x, f0, acc[0].x);
                acc[0].y = fmaf(wv.y, f0, acc[0].y);
                acc[0].z = fmaf(wv.z, f0, acc[0].z);
                acc[0].w = fmaf(wv.w, f0, acc[0].w);
                acc[1].x = fmaf(wv.x, f1, acc[1].x);
                acc[1].y = fmaf(wv.y, f1, acc[1].y);
                acc[1].z = fmaf(wv.z, f1, acc[1].z);
                acc[1].w = fmaf(wv.w, f1, acc[1].w);
                acc[2].x = fmaf(wv.x, f2, acc[2].x);
                acc[2].y = fmaf(wv.y, f2, acc[2].y);
                acc[2].z = fmaf(wv.z, f2, acc[2].z);
                acc[2].w = fmaf(wv.w, f2, acc[2].w);
                acc[3].x = fmaf(wv.x, f3, acc[3].x);
                acc[3].y = fmaf(wv.y, f3, acc[3].y);
                acc[3].z = fmaf(wv.z, f3, acc[3].z);
                acc[3].w = fmaf(wv.w, f3, acc[3].w);
            }

            #pragma unroll
            for (int j = 0; j < 4; ++j) {
                const int n = n0 + nn + j;
                const float px = posb[0 * N_ + n];
                const float py = posb[1 * N_ + n];
                const float pz = posb[2 * N_ + n];
                float4 a = acc[j];
                a.w = fmaf(-px, a.x, fmaf(-py, a.y, fmaf(-pz, a.z, a.w)));
                #pragma unroll
                for (int k = 0; k < K_; ++k) {
                    const int jt   = nbhb[k * N_ + n];
                    const int slot = smb[k * N_ + n];
                    const float qx = posb[0 * N_ + jt];
                    const float qy = posb[1 * N_ + jt];
                    const float qz = posb[2 * N_ + jt];
                    const float c  = fmaf(qx, a.x, fmaf(qy, a.y, fmaf(qz, a.z, a.w)));
                    cb[((size_t)slot << 6) + lane] = c;
                }
            }
        }
    }
}

__global__ __launch_bounds__(512) void fc_gather3(
    const float* __restrict__ contrib,
    const int*   __restrict__ offsets,
    const int*   __restrict__ counts,
    const float* __restrict__ bias,
    float*       __restrict__ out)
{
    __shared__ float T[64][65];
    const int tid  = threadIdx.x;
    const int lane = tid & 63;
    const int w    = tid >> 6;

    const int tiles_per_b = N_ / 64;
    const int b  = blockIdx.x / tiles_per_b;
    const int n0 = (blockIdx.x % tiles_per_b) * 64;

    const float* cb = contrib + ((size_t)b * EDGES_PER_B << 6);

    for (int g = 0; g < 8; ++g) {
        const int jj = w * 8 + g;
        const int j  = n0 + jj;
        const int base = offsets[b * N_ + j];
        const int cnt  = counts[b * N_ + j];

        const float* p = cb + ((size_t)base << 6) + lane;
        float acc = 0.f;
        int e = 0;
        for (; e + 4 <= cnt; e += 4) {
            const float v0 = p[0];
            const float v1 = p[64];
            const float v2 = p[128];
            const float v3 = p[192];
            acc += (v0 + v1) + (v2 + v3);
            p += 256;
        }
        for (; e < cnt; ++e) { acc += *p; p += 64; }
        T[jj][lane] = acc;
    }
    __syncthreads();

    float* outb = out + (size_t)b * COUT_ * N_;
    for (int r = 0; r < 8; ++r) {
        const int o = r * 8 + w;
        outb[(size_t)o * N_ + n0 + lane] = T[lane][o] + bias[o];
    }
}

// ===========================================================================
// PATH C (16 MiB ws): verified atomic-scatter fallback.
// ===========================================================================
__global__ __launch_bounds__(256) void flexconv_main(
    const float* __restrict__ feat,
    const float* __restrict__ theta,
    const float* __restrict__ wbias,
    const int*   __restrict__ nbh,
    const float* __restrict__ pos,
    float*       __restrict__ ws)
{
    __shared__ float4 Wl[CIN_ * COUT_];
    __shared__ float  Fl[CIN_ * 64];

    const int tid  = threadIdx.x;
    const int lane = tid & 63;
    const int w    = tid >> 6;

    const int blocks_per_b = N_ / 128;
    const int b     = blockIdx.x / blocks_per_b;
    const int nbase = (blockIdx.x % blocks_per_b) * 128;

    for (int e = tid; e < CIN_ * COUT_; e += 256) {
        const int i = e >> 6, o = e & 63;
        float4 wv;
        wv.x = theta[0 * CIN_ * COUT_ + i * COUT_ + o];
        wv.y = theta[1 * CIN_ * COUT_ + i * COUT_ + o];
        wv.z = theta[2 * CIN_ * COUT_ + i * COUT_ + o];
        wv.w = wbias[i * COUT_ + o];
        Wl[e] = wv;
    }

    const float* featb = feat + (size_t)b * CIN_ * N_;
    const float* posb  = pos  + (size_t)b * 3 * N_;
    const int*   nbhb  = nbh  + (size_t)b * K_ * N_;
    float*       wsb   = ws   + (size_t)b * N_ * COUT_;

    for (int t = 0; t < 2; ++t) {
        const int n0 = nbase + t * 64;

        __syncthreads();
        for (int r = 0; r < 16; ++r) {
            const int i = r * 4 + w;
            Fl[i * 64 + lane] = featb[(size_t)i * N_ + n0 + lane];
        }
        __syncthreads();

        for (int g = 0; g < 4; ++g) {
            const int nn = w * 16 + g * 4;
            float4 acc[4];
            #pragma unroll
            for (int j = 0; j < 4; ++j) acc[j] = make_float4(0.f, 0.f, 0.f, 0.f);

            #pragma unroll 8
            for (int i = 0; i < CIN_; ++i) {
                const float4 wv = Wl[i * 64 + lane];
                const float f0 = Fl[i * 64 + nn + 0];
                const float f1 = Fl[i * 64 + nn + 1];
                const float f2 = Fl[i * 64 + nn + 2];
                const float f3 = Fl[i * 64 + nn + 3];
                acc[0].x = fmaf(wv.x, f0, acc[0].x);
                acc[0].y = fmaf(wv.y, f0, acc[0].y);
                acc[0].z = fmaf(wv.z, f0, acc[0].z);
                acc[0].w = fmaf(wv.w, f0, acc[0].w);
                acc[1].x = fmaf(wv.x, f1, acc[1].x);
                acc[1].y = fmaf(wv.y, f1, acc[1].y);
                acc[1].z = fmaf(wv.z, f1, acc[1].z);
                acc[1].w = fmaf(wv.w, f1, acc[1].w);
                acc[2].x = fmaf(wv.x, f2, acc[2].x);
                acc[2].y = fmaf(wv.y, f2, acc[2].y);
                acc[2].z = fmaf(wv.z, f2, acc[2].z);
                acc[2].w = fmaf(wv.w, f2, acc[2].w);
                acc[3].x = fmaf(wv.x, f3, acc[3].x);
                acc[3].y = fmaf(wv.y, f3, acc[3].y);
                acc[3].z = fmaf(wv.z, f3, acc[3].z);
                acc[3].w = fmaf(wv.w, f3, acc[3].w);
            }

            #pragma unroll
            for (int j = 0; j < 4; ++j) {
                const int n = n0 + nn + j;
                const float px = posb[0 * N_ + n];
                const float py = posb[1 * N_ + n];
                const float pz = posb[2 * N_ + n];
                const float4 a = acc[j];
                #pragma unroll
                for (int k = 0; k < K_; ++k) {
                    const int idx = nbhb[k * N_ + n];
                    const float dx = posb[0 * N_ + idx] - px;
                    const float dy = posb[1 * N_ + idx] - py;
                    const float dz = posb[2 * N_ + idx] - pz;
                    const float c  = fmaf(dx, a.x, fmaf(dy, a.y, fmaf(dz, a.z, a.w)));
                    atomicAdd(&wsb[(size_t)idx * COUT_ + lane], c);
                }
            }
        }
    }
}

__global__ __launch_bounds__(256) void flexconv_finish(
    const float* __restrict__ ws,
    const float* __restrict__ bias,
    float*       __restrict__ out)
{
    __shared__ float T[64][65];
    const int tid  = threadIdx.x;
    const int lane = tid & 63;
    const int w    = tid >> 6;

    const int tiles_per_b = N_ / 64;
    const int b  = blockIdx.x / tiles_per_b;
    const int n0 = (blockIdx.x % tiles_per_b) * 64;

    const float* wsb = ws + (size_t)b * N_ * COUT_;
    for (int r = 0; r < 16; ++r) {
        const int nn = r * 4 + w;
        T[nn][lane] = wsb[(size_t)(n0 + nn) * COUT_ + lane];
    }
    __syncthreads();

    float* outb = out + (size_t)b * COUT_ * N_;
    for (int r = 0; r < 16; ++r) {
        const int o = r * 4 + w;
        outb[(size_t)o * N_ + n0 + lane] = T[lane][o] + bias[o];
    }
}

// ===========================================================================
extern "C" void kernel_launch(void* const* d_in, const int* in_sizes, int n_in,
                              void* d_out, int out_size, void* d_ws, size_t ws_size,
                              hipStream_t stream) {
    const float* features = (const float*)d_in[0];
    const float* theta    = (const float*)d_in[1];
    const float* wbias    = (const float*)d_in[2];
    const int*   nbh      = (const int*)  d_in[3];
    const float* pos      = (const float*)d_in[4];
    const float* bias     = (const float*)d_in[5];
    float* out = (float*)d_out;

    const size_t contrib_bytes = (size_t)TOT_EDGES * COUT_ * sizeof(float); // 128 MiB
    const size_t counts_bytes  = (size_t)B_ * N_ * sizeof(int);             // 256 KiB
    const size_t map_bytes     = (size_t)TOT_EDGES * sizeof(int);           // 2 MiB
    const size_t rec_bytes     = (size_t)TOT_EDGES * sizeof(float4);        // 8 MiB

    // ---- Path A-new: contrib + offsets + counts + rec (~136.5 MiB) ----
    {
        size_t off = 0;
        float*  contrib = (float*) ((char*)d_ws + off); off += contrib_bytes;
        int*    offsets = (int*)   ((char*)d_ws + off); off += counts_bytes;
        int*    counts  = (int*)   ((char*)d_ws + off); off += counts_bytes;
        float4* rec     = (float4*)((char*)d_ws + off); off += rec_bytes;

        if (ws_size >= off) {
            fc_prep<<<B_, 1024, 0, stream>>>(nbh, pos, offsets, counts, rec);
            fc_contribA<<<B_ * (N_ / 128), 512, 0, stream>>>(features, theta, wbias,
                                                             rec, pos, contrib);
            fc_gatherA<<<B_ * (N_ / 64), 512, 0, stream>>>(contrib, offsets, counts,
                                                           bias, out);
            return;
        }
    }

    // ---- Path A-old: round-2 pipeline (~131 MiB) ----
    {
        size_t off = 0;
        float* contrib = (float*)((char*)d_ws + off); off += contrib_bytes;
        int* counts  = (int*)((char*)d_ws + off); off += counts_bytes;
        int* offsets = (int*)((char*)d_ws + off); off += counts_bytes;
        int* cursor  = (int*)((char*)d_ws + off); off += counts_bytes;
        int* slotmap = (int*)((char*)d_ws + off); off += map_bytes;

        if (ws_size >= off) {
            hipMemsetAsync(counts, 0, counts_bytes, stream);
            fc_hist<<<TOT_EDGES / 256, 256, 0, stream>>>(nbh, counts);
            fc_scan<<<B_, 256, 0, stream>>>(counts, offsets, cursor);
            fc_fill_slot<<<TOT_EDGES / 256, 256, 0, stream>>>(nbh, cursor, slotmap);
            fc_contrib<<<B_ * (N_ / 128), 256, 0, stream>>>(features, theta, wbias,
                                                            nbh, slotmap, pos, contrib);
            fc_gather3<<<B_ * (N_ / 64), 512, 0, stream>>>(contrib, offsets, counts,
                                                           bias, out);
            return;
        }
    }

    // ---- Path C: atomic fallback (16 MiB) ----
    {
        float* ws = (float*)d_ws;
        const size_t ws_bytes = (size_t)B_ * N_ * COUT_ * sizeof(float);
        hipMemsetAsync(ws, 0, ws_bytes, stream);
        flexconv_main<<<B_ * (N_ / 128), 256, 0, stream>>>(features, theta, wbias,
                                                           nbh, pos, ws);
        flexconv_finish<<<B_ * (N_ / 64), 256, 0, stream>>>(ws, bias, out);
    }
}

// Round 4
// 195.633 us; speedup vs baseline: 2.4527x; 2.4527x over previous
//
#include <hip/hip_runtime.h>

#define B_    4
#define CIN_  64
#define COUT_ 64
#define N_    16384
#define K_    8

#define EDGES_PER_B (K_ * N_)            // 131072
#define TOT_EDGES   (B_ * EDGES_PER_B)   // 524288

// ===========================================================================
// Shared prep kernels (counting sort of edges by target j) — wide grids.
// ===========================================================================

// --- histogram of incoming-edge counts per target point j ------------------
__global__ __launch_bounds__(256) void fc_hist(
    const int* __restrict__ nbh,      // [B, K, N] flat
    int*       __restrict__ counts)   // [B, N]
{
    const int gid = blockIdx.x * 256 + threadIdx.x;     // < TOT_EDGES
    const int b   = gid / EDGES_PER_B;
    const int j   = nbh[gid];
    atomicAdd(&counts[b * N_ + j], 1);
}

// --- per-batch exclusive scan of counts -> offsets (+ cursor copy) ---------
__global__ __launch_bounds__(256) void fc_scan(
    const int* __restrict__ counts,
    int*       __restrict__ offsets,
    int*       __restrict__ cursor)
{
    __shared__ int s[256];
    const int b = blockIdx.x;
    const int t = threadIdx.x;
    const int base = b * N_ + t * 64;   // each thread owns 64 consecutive bins

    int sum = 0;
    #pragma unroll
    for (int e = 0; e < 64; ++e) sum += counts[base + e];
    s[t] = sum;
    __syncthreads();

    for (int d = 1; d < 256; d <<= 1) {
        const int v = (t >= d) ? s[t - d] : 0;
        __syncthreads();
        s[t] += v;
        __syncthreads();
    }

    int off = s[t] - sum;               // exclusive base for this chunk
    #pragma unroll
    for (int e = 0; e < 64; ++e) {
        const int c = counts[base + e];
        offsets[base + e] = off;
        cursor[base + e]  = off;
        off += c;
    }
}

// --- build per-edge records: {pos_j, slot} — one thread per source point n -
__global__ __launch_bounds__(256) void fc_rec(
    const int*   __restrict__ nbh,      // [B, K, N]
    const float* __restrict__ pos,      // [B, 3, N]
    int*         __restrict__ cursor,   // [B, N]
    float4*      __restrict__ rec)      // [B, N, K] {qx,qy,qz, slot}
{
    const int gid = blockIdx.x * 256 + threadIdx.x;     // < B_*N_
    const int b   = gid >> 14;                          // / N_
    const int n   = gid & (N_ - 1);

    const int*   nbhb = nbh + (size_t)b * K_ * N_;
    const float* posb = pos + (size_t)b * 3 * N_;
    float4*      recb = rec + ((size_t)b * N_ + n) * K_;

    #pragma unroll
    for (int k = 0; k < K_; ++k) {
        const int j    = nbhb[k * N_ + n];              // coalesced
        const int slot = atomicAdd(&cursor[b * N_ + j], 1);   // L2-resident
        const float qx = posb[j];                       // L2-resident gathers
        const float qy = posb[N_ + j];
        const float qz = posb[2 * N_ + j];
        recb[k] = make_float4(qx, qy, qz, __int_as_float(slot));  // 128 B/thread
    }
}

// ===========================================================================
// PATH A (~137 MiB ws): high-occupancy contrib + vectorized gather.
// contribA / gatherA byte-identical to the round-3 verified versions.
// ===========================================================================

__global__ __launch_bounds__(512, 4) void fc_contribA(
    const float*  __restrict__ feat,    // [B, CIN, N]
    const float*  __restrict__ theta,   // [3, CIN, COUT]
    const float*  __restrict__ wbias,   // [CIN, COUT]
    const float4* __restrict__ rec,     // [B, N, K]
    const float*  __restrict__ pos,     // [B, 3, N]
    float*        __restrict__ contrib) // [B, K*N, COUT]
{
    __shared__ float4 Wl[CIN_ * COUT_];   // 64 KiB
    __shared__ float  Fl[CIN_ * 64];      // 16 KiB

    const int tid  = threadIdx.x;
    const int lane = tid & 63;            // o
    const int w    = tid >> 6;            // wave 0..7

    const int blocks_per_b = N_ / 128;    // 128
    const int b     = blockIdx.x / blocks_per_b;
    const int nbase = (blockIdx.x % blocks_per_b) * 128;

    for (int e = tid; e < CIN_ * COUT_; e += 512) {
        const int i = e >> 6, o = e & 63;
        float4 wv;
        wv.x = theta[0 * CIN_ * COUT_ + i * COUT_ + o];
        wv.y = theta[1 * CIN_ * COUT_ + i * COUT_ + o];
        wv.z = theta[2 * CIN_ * COUT_ + i * COUT_ + o];
        wv.w = wbias[i * COUT_ + o];
        Wl[e] = wv;
    }

    const float*  featb = feat + (size_t)b * CIN_ * N_;
    const float*  posb  = pos  + (size_t)b * 3 * N_;
    const float4* recb  = rec  + (size_t)b * N_ * K_;
    float*        cb    = contrib + ((size_t)b * EDGES_PER_B << 6);

    for (int t = 0; t < 2; ++t) {
        const int n0 = nbase + t * 64;

        __syncthreads();   // Wl ready (t=0) / previous Fl readers done (t=1)
        for (int r = 0; r < 8; ++r) {
            const int i = r * 8 + w;
            Fl[i * 64 + lane] = featb[(size_t)i * N_ + n0 + lane];
        }
        __syncthreads();

        // each wave: 8 points (nn..nn+7)
        const int nn = w * 8;
        float4 acc[8];
        #pragma unroll
        for (int j = 0; j < 8; ++j) acc[j] = make_float4(0.f, 0.f, 0.f, 0.f);

        #pragma unroll 2
        for (int i = 0; i < CIN_; ++i) {
            const float4 wv = Wl[i * 64 + lane];              // conflict-free b128
            const float4 fA = *(const float4*)&Fl[i * 64 + nn];     // broadcast
            const float4 fB = *(const float4*)&Fl[i * 64 + nn + 4]; // broadcast
            const float fs[8] = {fA.x, fA.y, fA.z, fA.w, fB.x, fB.y, fB.z, fB.w};
            #pragma unroll
            for (int j = 0; j < 8; ++j) {
                acc[j].x = fmaf(wv.x, fs[j], acc[j].x);
                acc[j].y = fmaf(wv.y, fs[j], acc[j].y);
                acc[j].z = fmaf(wv.z, fs[j], acc[j].z);
                acc[j].w = fmaf(wv.w, fs[j], acc[j].w);
            }
        }

        #pragma unroll
        for (int j = 0; j < 8; ++j) {
            const int n = n0 + nn + j;
            const float px = posb[0 * N_ + n];
            const float py = posb[1 * N_ + n];
            const float pz = posb[2 * N_ + n];
            float4 a = acc[j];
            a.w = fmaf(-px, a.x, fmaf(-py, a.y, fmaf(-pz, a.z, a.w)));  // h
            #pragma unroll
            for (int k = 0; k < K_; ++k) {
                const float4 r = recb[(size_t)n * K_ + k];    // contiguous bcast
                const int slot = __float_as_int(r.w);
                const float c  = fmaf(r.x, a.x, fmaf(r.y, a.y, fmaf(r.z, a.z, a.w)));
                cb[((size_t)slot << 6) + lane] = c;           // 256 B / wave
            }
        }
    }
}

__global__ __launch_bounds__(512) void fc_gatherA(
    const float* __restrict__ contrib,
    const int*   __restrict__ offsets,
    const int*   __restrict__ counts,
    const float* __restrict__ bias,
    float*       __restrict__ out)     // [B, COUT, N]
{
    __shared__ float T[64][65];
    __shared__ float V[64][65];
    const int tid  = threadIdx.x;
    const int lane = tid & 63;
    const int w    = tid >> 6;            // 0..7

    const int tiles_per_b = N_ / 64;      // 256
    const int b  = blockIdx.x / tiles_per_b;
    const int n0 = (blockIdx.x % tiles_per_b) * 64;

    const float*  cb  = contrib + ((size_t)b * EDGES_PER_B << 6);
    const float4* cb4 = (const float4*)cb;

    for (int g = 0; g < 8; ++g) {
        const int jj = w * 8 + g;
        const int j  = n0 + jj;
        const int base = offsets[b * N_ + j];
        const int cnt  = counts[b * N_ + j];

        // vector part: lane l covers row-offset (l>>4), channels 4*(l&15)+c
        const float4* p4 = cb4 + (size_t)base * 16 + lane;
        float4 v = make_float4(0.f, 0.f, 0.f, 0.f);
        const int full = cnt >> 2;          // groups of 4 rows
        int it = 0;
        for (; it + 2 <= full; it += 2) {   // 2 in flight
            const float4 a0 = p4[0];
            const float4 a1 = p4[64];
            v.x += a0.x + a1.x; v.y += a0.y + a1.y;
            v.z += a0.z + a1.z; v.w += a0.w + a1.w;
            p4 += 128;
        }
        if (it < full) {
            const float4 a0 = p4[0];
            v.x += a0.x; v.y += a0.y; v.z += a0.z; v.w += a0.w;
        }
        // reduce the 4 lanes sharing each channel set (l, l+16, l+32, l+48)
        v.x += __shfl_xor(v.x, 16); v.y += __shfl_xor(v.y, 16);
        v.z += __shfl_xor(v.z, 16); v.w += __shfl_xor(v.w, 16);
        v.x += __shfl_xor(v.x, 32); v.y += __shfl_xor(v.y, 32);
        v.z += __shfl_xor(v.z, 32); v.w += __shfl_xor(v.w, 32);

        // scalar tail rows
        float tail = 0.f;
        const float* pt = cb + (((size_t)base + ((size_t)full << 2)) << 6) + lane;
        for (int e = full << 2; e < cnt; ++e) { tail += *pt; pt += 64; }

        T[jj][lane] = tail;
        if (lane < 16) {
            V[jj][4 * lane + 0] = v.x;
            V[jj][4 * lane + 1] = v.y;
            V[jj][4 * lane + 2] = v.z;
            V[jj][4 * lane + 3] = v.w;
        }
    }
    __syncthreads();

    float* outb = out + (size_t)b * COUT_ * N_;
    for (int r = 0; r < 8; ++r) {
        const int o = r * 8 + w;
        outb[(size_t)o * N_ + n0 + lane] = T[lane][o] + V[lane][o] + bias[o];
    }
}

// ===========================================================================
// PATH A-OLD (~131 MiB ws): round-2 verified pipeline (fallback).
// ===========================================================================

__global__ __launch_bounds__(256) void fc_fill_slot(
    const int* __restrict__ nbh,
    int*       __restrict__ cursor,
    int*       __restrict__ slotmap)
{
    const int gid = blockIdx.x * 256 + threadIdx.x;
    const int b   = gid / EDGES_PER_B;
    const int j   = nbh[gid];
    slotmap[gid] = atomicAdd(&cursor[b * N_ + j], 1);
}

__global__ __launch_bounds__(256) void fc_contrib(
    const float* __restrict__ feat,
    const float* __restrict__ theta,
    const float* __restrict__ wbias,
    const int*   __restrict__ nbh,
    const int*   __restrict__ slotmap,
    const float* __restrict__ pos,
    float*       __restrict__ contrib)
{
    __shared__ float4 Wl[CIN_ * COUT_];
    __shared__ float  Fl[CIN_ * 64];

    const int tid  = threadIdx.x;
    const int lane = tid & 63;
    const int w    = tid >> 6;

    const int blocks_per_b = N_ / 128;
    const int b     = blockIdx.x / blocks_per_b;
    const int nbase = (blockIdx.x % blocks_per_b) * 128;

    for (int e = tid; e < CIN_ * COUT_; e += 256) {
        const int i = e >> 6, o = e & 63;
        float4 wv;
        wv.x = theta[0 * CIN_ * COUT_ + i * COUT_ + o];
        wv.y = theta[1 * CIN_ * COUT_ + i * COUT_ + o];
        wv.z = theta[2 * CIN_ * COUT_ + i * COUT_ + o];
        wv.w = wbias[i * COUT_ + o];
        Wl[e] = wv;
    }

    const float* featb = feat + (size_t)b * CIN_ * N_;
    const float* posb  = pos  + (size_t)b * 3 * N_;
    const int*   nbhb  = nbh  + (size_t)b * K_ * N_;
    const int*   smb   = slotmap + (size_t)b * EDGES_PER_B;
    float*       cb    = contrib + ((size_t)b * EDGES_PER_B << 6);

    for (int t = 0; t < 2; ++t) {
        const int n0 = nbase + t * 64;

        __syncthreads();
        for (int r = 0; r < 16; ++r) {
            const int i = r * 4 + w;
            Fl[i * 64 + lane] = featb[(size_t)i * N_ + n0 + lane];
        }
        __syncthreads();

        for (int g = 0; g < 4; ++g) {
            const int nn = w * 16 + g * 4;
            float4 acc[4];
            #pragma unroll
            for (int j = 0; j < 4; ++j) acc[j] = make_float4(0.f, 0.f, 0.f, 0.f);

            #pragma unroll 8
            for (int i = 0; i < CIN_; ++i) {
                const float4 wv = Wl[i * 64 + lane];
                const float f0 = Fl[i * 64 + nn + 0];
                const float f1 = Fl[i * 64 + nn + 1];
                const float f2 = Fl[i * 64 + nn + 2];
                const float f3 = Fl[i * 64 + nn + 3];
                acc[0].x = fmaf(wv.x, f0, acc[0].x);
                acc[0].y = fmaf(wv.y, f0, acc[0].y);
                acc[0].z = fmaf(wv.z, f0, acc[0].z);
                acc[0].w = fmaf(wv.w, f0, acc[0].w);
                acc[1].x = fmaf(wv.x, f1, acc[1].x);
                acc[1].y = fmaf(wv.y, f1, acc[1].y);
                acc[1].z = fmaf(wv.z, f1, acc[1].z);
                acc[1].w = fmaf(wv.w, f1, acc[1].w);
                acc[2].x = fmaf(wv.x, f2, acc[2].x);
                acc[2].y = fmaf(wv.y, f2, acc[2].y);
                acc[2].z = fmaf(wv.z, f2, acc[2].z);
                acc[2].w = fmaf(wv.w, f2, acc[2].w);
                acc[3].x = fmaf(wv.x, f3, acc[3].x);
                acc[3].y = fmaf(wv.y, f3, acc[3].y);
                acc[3].z = fmaf(wv.z, f3, acc[3].z);
                acc[3].w = fmaf(wv.w, f3, acc[3].w);
            }

            #pragma unroll
            for (int j = 0; j < 4; ++j) {
                const int n = n0 + nn + j;
                const float px = posb[0 * N_ + n];
                const float py = posb[1 * N_ + n];
                const float pz = posb[2 * N_ + n];
                float4 a = acc[j];
                a.w = fmaf(-px, a.x, fmaf(-py, a.y, fmaf(-pz, a.z, a.w)));
                #pragma unroll
                for (int k = 0; k < K_; ++k) {
                    const int jt   = nbhb[k * N_ + n];
                    const int slot = smb[k * N_ + n];
                    const float qx = posb[0 * N_ + jt];
                    const float qy = posb[1 * N_ + jt];
                    const float qz = posb[2 * N_ + jt];
                    const float c  = fmaf(qx, a.x, fmaf(qy, a.y, fmaf(qz, a.z, a.w)));
                    cb[((size_t)slot << 6) + lane] = c;
                }
            }
        }
    }
}

__global__ __launch_bounds__(512) void fc_gather3(
    const float* __restrict__ contrib,
    const int*   __restrict__ offsets,
    const int*   __restrict__ counts,
    const float* __restrict__ bias,
    float*       __restrict__ out)
{
    __shared__ float T[64][65];
    const int tid  = threadIdx.x;
    const int lane = tid & 63;
    const int w    = tid >> 6;

    const int tiles_per_b = N_ / 64;
    const int b  = blockIdx.x / tiles_per_b;
    const int n0 = (blockIdx.x % tiles_per_b) * 64;

    const float* cb = contrib + ((size_t)b * EDGES_PER_B << 6);

    for (int g = 0; g < 8; ++g) {
        const int jj = w * 8 + g;
        const int j  = n0 + jj;
        const int base = offsets[b * N_ + j];
        const int cnt  = counts[b * N_ + j];

        const float* p = cb + ((size_t)base << 6) + lane;
        float acc = 0.f;
        int e = 0;
        for (; e + 4 <= cnt; e += 4) {
            const float v0 = p[0];
            const float v1 = p[64];
            const float v2 = p[128];
            const float v3 = p[192];
            acc += (v0 + v1) + (v2 + v3);
            p += 256;
        }
        for (; e < cnt; ++e) { acc += *p; p += 64; }
        T[jj][lane] = acc;
    }
    __syncthreads();

    float* outb = out + (size_t)b * COUT_ * N_;
    for (int r = 0; r < 8; ++r) {
        const int o = r * 8 + w;
        outb[(size_t)o * N_ + n0 + lane] = T[lane][o] + bias[o];
    }
}

// ===========================================================================
// PATH C (16 MiB ws): verified atomic-scatter fallback.
// ===========================================================================
__global__ __launch_bounds__(256) void flexconv_main(
    const float* __restrict__ feat,
    const float* __restrict__ theta,
    const float* __restrict__ wbias,
    const int*   __restrict__ nbh,
    const float* __restrict__ pos,
    float*       __restrict__ ws)
{
    __shared__ float4 Wl[CIN_ * COUT_];
    __shared__ float  Fl[CIN_ * 64];

    const int tid  = threadIdx.x;
    const int lane = tid & 63;
    const int w    = tid >> 6;

    const int blocks_per_b = N_ / 128;
    const int b     = blockIdx.x / blocks_per_b;
    const int nbase = (blockIdx.x % blocks_per_b) * 128;

    for (int e = tid; e < CIN_ * COUT_; e += 256) {
        const int i = e >> 6, o = e & 63;
        float4 wv;
        wv.x = theta[0 * CIN_ * COUT_ + i * COUT_ + o];
        wv.y = theta[1 * CIN_ * COUT_ + i * COUT_ + o];
        wv.z = theta[2 * CIN_ * COUT_ + i * COUT_ + o];
        wv.w = wbias[i * COUT_ + o];
        Wl[e] = wv;
    }

    const float* featb = feat + (size_t)b * CIN_ * N_;
    const float* posb  = pos  + (size_t)b * 3 * N_;
    const int*   nbhb  = nbh  + (size_t)b * K_ * N_;
    float*       wsb   = ws   + (size_t)b * N_ * COUT_;

    for (int t = 0; t < 2; ++t) {
        const int n0 = nbase + t * 64;

        __syncthreads();
        for (int r = 0; r < 16; ++r) {
            const int i = r * 4 + w;
            Fl[i * 64 + lane] = featb[(size_t)i * N_ + n0 + lane];
        }
        __syncthreads();

        for (int g = 0; g < 4; ++g) {
            const int nn = w * 16 + g * 4;
            float4 acc[4];
            #pragma unroll
            for (int j = 0; j < 4; ++j) acc[j] = make_float4(0.f, 0.f, 0.f, 0.f);

            #pragma unroll 8
            for (int i = 0; i < CIN_; ++i) {
                const float4 wv = Wl[i * 64 + lane];
                const float f0 = Fl[i * 64 + nn + 0];
                const float f1 = Fl[i * 64 + nn + 1];
                const float f2 = Fl[i * 64 + nn + 2];
                const float f3 = Fl[i * 64 + nn + 3];
                acc[0].x = fmaf(wv.x, f0, acc[0].x);
                acc[0].y = fmaf(wv.y, f0, acc[0].y);
                acc[0].z = fmaf(wv.z, f0, acc[0].z);
                acc[0].w = fmaf(wv.w, f0, acc[0].w);
                acc[1].x = fmaf(wv.x, f1, acc[1].x);
                acc[1].y = fmaf(wv.y, f1, acc[1].y);
                acc[1].z = fmaf(wv.z, f1, acc[1].z);
                acc[1].w = fmaf(wv.w, f1, acc[1].w);
                acc[2].x = fmaf(wv.x, f2, acc[2].x);
                acc[2].y = fmaf(wv.y, f2, acc[2].y);
                acc[2].z = fmaf(wv.z, f2, acc[2].z);
                acc[2].w = fmaf(wv.w, f2, acc[2].w);
                acc[3].x = fmaf(wv.x, f3, acc[3].x);
                acc[3].y = fmaf(wv.y, f3, acc[3].y);
                acc[3].z = fmaf(wv.z, f3, acc[3].z);
                acc[3].w = fmaf(wv.w, f3, acc[3].w);
            }

            #pragma unroll
            for (int j = 0; j < 4; ++j) {
                const int n = n0 + nn + j;
                const float px = posb[0 * N_ + n];
                const float py = posb[1 * N_ + n];
                const float pz = posb[2 * N_ + n];
                const float4 a = acc[j];
                #pragma unroll
                for (int k = 0; k < K_; ++k) {
                    const int idx = nbhb[k * N_ + n];
                    const float dx = posb[0 * N_ + idx] - px;
                    const float dy = posb[1 * N_ + idx] - py;
                    const float dz = posb[2 * N_ + idx] - pz;
                    const float c  = fmaf(dx, a.x, fmaf(dy, a.y, fmaf(dz, a.z, a.w)));
                    atomicAdd(&wsb[(size_t)idx * COUT_ + lane], c);
                }
            }
        }
    }
}

__global__ __launch_bounds__(256) void flexconv_finish(
    const float* __restrict__ ws,
    const float* __restrict__ bias,
    float*       __restrict__ out)
{
    __shared__ float T[64][65];
    const int tid  = threadIdx.x;
    const int lane = tid & 63;
    const int w    = tid >> 6;

    const int tiles_per_b = N_ / 64;
    const int b  = blockIdx.x / tiles_per_b;
    const int n0 = (blockIdx.x % tiles_per_b) * 64;

    const float* wsb = ws + (size_t)b * N_ * COUT_;
    for (int r = 0; r < 16; ++r) {
        const int nn = r * 4 + w;
        T[nn][lane] = wsb[(size_t)(n0 + nn) * COUT_ + lane];
    }
    __syncthreads();

    float* outb = out + (size_t)b * COUT_ * N_;
    for (int r = 0; r < 16; ++r) {
        const int o = r * 4 + w;
        outb[(size_t)o * N_ + n0 + lane] = T[lane][o] + bias[o];
    }
}

// ===========================================================================
extern "C" void kernel_launch(void* const* d_in, const int* in_sizes, int n_in,
                              void* d_out, int out_size, void* d_ws, size_t ws_size,
                              hipStream_t stream) {
    const float* features = (const float*)d_in[0];
    const float* theta    = (const float*)d_in[1];
    const float* wbias    = (const float*)d_in[2];
    const int*   nbh      = (const int*)  d_in[3];
    const float* pos      = (const float*)d_in[4];
    const float* bias     = (const float*)d_in[5];
    float* out = (float*)d_out;

    const size_t contrib_bytes = (size_t)TOT_EDGES * COUT_ * sizeof(float); // 128 MiB
    const size_t counts_bytes  = (size_t)B_ * N_ * sizeof(int);             // 256 KiB
    const size_t map_bytes     = (size_t)TOT_EDGES * sizeof(int);           // 2 MiB
    const size_t rec_bytes     = (size_t)TOT_EDGES * sizeof(float4);        // 8 MiB

    // ---- Path A: contrib + offsets + counts + cursor + rec (~137 MiB) ----
    {
        size_t off = 0;
        float*  contrib = (float*) ((char*)d_ws + off); off += contrib_bytes;
        int*    offsets = (int*)   ((char*)d_ws + off); off += counts_bytes;
        int*    counts  = (int*)   ((char*)d_ws + off); off += counts_bytes;
        int*    cursor  = (int*)   ((char*)d_ws + off); off += counts_bytes;
        float4* rec     = (float4*)((char*)d_ws + off); off += rec_bytes;

        if (ws_size >= off) {
            hipMemsetAsync(counts, 0, counts_bytes, stream);
            fc_hist<<<TOT_EDGES / 256, 256, 0, stream>>>(nbh, counts);
            fc_scan<<<B_, 256, 0, stream>>>(counts, offsets, cursor);
            fc_rec<<<(B_ * N_) / 256, 256, 0, stream>>>(nbh, pos, cursor, rec);
            fc_contribA<<<B_ * (N_ / 128), 512, 0, stream>>>(features, theta, wbias,
                                                             rec, pos, contrib);
            fc_gatherA<<<B_ * (N_ / 64), 512, 0, stream>>>(contrib, offsets, counts,
                                                           bias, out);
            return;
        }
    }

    // ---- Path A-old: round-2 pipeline (~131 MiB) ----
    {
        size_t off = 0;
        float* contrib = (float*)((char*)d_ws + off); off += contrib_bytes;
        int* counts  = (int*)((char*)d_ws + off); off += counts_bytes;
        int* offsets = (int*)((char*)d_ws + off); off += counts_bytes;
        int* cursor  = (int*)((char*)d_ws + off); off += counts_bytes;
        int* slotmap = (int*)((char*)d_ws + off); off += map_bytes;

        if (ws_size >= off) {
            hipMemsetAsync(counts, 0, counts_bytes, stream);
            fc_hist<<<TOT_EDGES / 256, 256, 0, stream>>>(nbh, counts);
            fc_scan<<<B_, 256, 0, stream>>>(counts, offsets, cursor);
            fc_fill_slot<<<TOT_EDGES / 256, 256, 0, stream>>>(nbh, cursor, slotmap);
            fc_contrib<<<B_ * (N_ / 128), 256, 0, stream>>>(features, theta, wbias,
                                                            nbh, slotmap, pos, contrib);
            fc_gather3<<<B_ * (N_ / 64), 512, 0, stream>>>(contrib, offsets, counts,
                                                           bias, out);
            return;
        }
    }

    // ---- Path C: atomic fallback (16 MiB) ----
    {
        float* ws = (float*)d_ws;
        const size_t ws_bytes = (size_t)B_ * N_ * COUT_ * sizeof(float);
        hipMemsetAsync(ws, 0, ws_bytes, stream);
        flexconv_main<<<B_ * (N_ / 128), 256, 0, stream>>>(features, theta, wbias,
                                                           nbh, pos, ws);
        flexconv_finish<<<B_ * (N_ / 64), 256, 0, stream>>>(ws, bias, out);
    }
}

// Round 5
// 190.060 us; speedup vs baseline: 2.5246x; 1.0293x over previous
//
#include <hip/hip_runtime.h>
#include <hip/hip_fp16.h>

#define B_    4
#define CIN_  64
#define COUT_ 64
#define N_    16384
#define K_    8

#define EDGES_PER_B (K_ * N_)            // 131072
#define TOT_EDGES   (B_ * EDGES_PER_B)   // 524288

// ===========================================================================
// Shared prep kernels (counting sort of edges by target j) — wide grids.
// ===========================================================================

// --- histogram of incoming-edge counts per target point j ------------------
__global__ __launch_bounds__(256) void fc_hist(
    const int* __restrict__ nbh,      // [B, K, N] flat
    int*       __restrict__ counts)   // [B, N]
{
    const int gid = blockIdx.x * 256 + threadIdx.x;     // < TOT_EDGES
    const int b   = gid / EDGES_PER_B;
    const int j   = nbh[gid];
    atomicAdd(&counts[b * N_ + j], 1);
}

// --- per-batch exclusive scan of counts -> offsets (+ cursor copy) ---------
__global__ __launch_bounds__(256) void fc_scan(
    const int* __restrict__ counts,
    int*       __restrict__ offsets,
    int*       __restrict__ cursor)
{
    __shared__ int s[256];
    const int b = blockIdx.x;
    const int t = threadIdx.x;
    const int base = b * N_ + t * 64;   // each thread owns 64 consecutive bins

    int sum = 0;
    #pragma unroll
    for (int e = 0; e < 64; ++e) sum += counts[base + e];
    s[t] = sum;
    __syncthreads();

    for (int d = 1; d < 256; d <<= 1) {
        const int v = (t >= d) ? s[t - d] : 0;
        __syncthreads();
        s[t] += v;
        __syncthreads();
    }

    int off = s[t] - sum;               // exclusive base for this chunk
    #pragma unroll
    for (int e = 0; e < 64; ++e) {
        const int c = counts[base + e];
        offsets[base + e] = off;
        cursor[base + e]  = off;
        off += c;
    }
}

// --- build per-edge records: {pos_j, slot} — one thread per source point n -
__global__ __launch_bounds__(256) void fc_rec(
    const int*   __restrict__ nbh,      // [B, K, N]
    const float* __restrict__ pos,      // [B, 3, N]
    int*         __restrict__ cursor,   // [B, N]
    float4*      __restrict__ rec)      // [B, N, K] {qx,qy,qz, slot}
{
    const int gid = blockIdx.x * 256 + threadIdx.x;     // < B_*N_
    const int b   = gid >> 14;                          // / N_
    const int n   = gid & (N_ - 1);

    const int*   nbhb = nbh + (size_t)b * K_ * N_;
    const float* posb = pos + (size_t)b * 3 * N_;
    float4*      recb = rec + ((size_t)b * N_ + n) * K_;

    #pragma unroll
    for (int k = 0; k < K_; ++k) {
        const int j    = nbhb[k * N_ + n];              // coalesced
        const int slot = atomicAdd(&cursor[b * N_ + j], 1);   // L2-resident
        const float qx = posb[j];                       // L2-resident gathers
        const float qy = posb[N_ + j];
        const float qz = posb[2 * N_ + j];
        recb[k] = make_float4(qx, qy, qz, __int_as_float(slot));  // 128 B/thread
    }
}

// ===========================================================================
// PATH A (~73 MiB ws): fp16 contrib — halves the dominant intermediate traffic.
// Structure identical to the round-4 verified kernels; only the contrib dtype
// changed (fp32 -> fp16 store, fp32 accumulate in gather).
// ===========================================================================

__global__ __launch_bounds__(512, 4) void fc_contribA(
    const float*  __restrict__ feat,    // [B, CIN, N]
    const float*  __restrict__ theta,   // [3, CIN, COUT]
    const float*  __restrict__ wbias,   // [CIN, COUT]
    const float4* __restrict__ rec,     // [B, N, K]
    const float*  __restrict__ pos,     // [B, 3, N]
    __half*       __restrict__ contrib) // [B, K*N, COUT] fp16
{
    __shared__ float4 Wl[CIN_ * COUT_];   // 64 KiB
    __shared__ float  Fl[CIN_ * 64];      // 16 KiB

    const int tid  = threadIdx.x;
    const int lane = tid & 63;            // o
    const int w    = tid >> 6;            // wave 0..7

    const int blocks_per_b = N_ / 128;    // 128
    const int b     = blockIdx.x / blocks_per_b;
    const int nbase = (blockIdx.x % blocks_per_b) * 128;

    for (int e = tid; e < CIN_ * COUT_; e += 512) {
        const int i = e >> 6, o = e & 63;
        float4 wv;
        wv.x = theta[0 * CIN_ * COUT_ + i * COUT_ + o];
        wv.y = theta[1 * CIN_ * COUT_ + i * COUT_ + o];
        wv.z = theta[2 * CIN_ * COUT_ + i * COUT_ + o];
        wv.w = wbias[i * COUT_ + o];
        Wl[e] = wv;
    }

    const float*  featb = feat + (size_t)b * CIN_ * N_;
    const float*  posb  = pos  + (size_t)b * 3 * N_;
    const float4* recb  = rec  + (size_t)b * N_ * K_;
    __half*       cb    = contrib + ((size_t)b * EDGES_PER_B << 6);

    for (int t = 0; t < 2; ++t) {
        const int n0 = nbase + t * 64;

        __syncthreads();   // Wl ready (t=0) / previous Fl readers done (t=1)
        for (int r = 0; r < 8; ++r) {
            const int i = r * 8 + w;
            Fl[i * 64 + lane] = featb[(size_t)i * N_ + n0 + lane];
        }
        __syncthreads();

        // each wave: 8 points (nn..nn+7)
        const int nn = w * 8;
        float4 acc[8];
        #pragma unroll
        for (int j = 0; j < 8; ++j) acc[j] = make_float4(0.f, 0.f, 0.f, 0.f);

        #pragma unroll 2
        for (int i = 0; i < CIN_; ++i) {
            const float4 wv = Wl[i * 64 + lane];              // conflict-free b128
            const float4 fA = *(const float4*)&Fl[i * 64 + nn];     // broadcast
            const float4 fB = *(const float4*)&Fl[i * 64 + nn + 4]; // broadcast
            const float fs[8] = {fA.x, fA.y, fA.z, fA.w, fB.x, fB.y, fB.z, fB.w};
            #pragma unroll
            for (int j = 0; j < 8; ++j) {
                acc[j].x = fmaf(wv.x, fs[j], acc[j].x);
                acc[j].y = fmaf(wv.y, fs[j], acc[j].y);
                acc[j].z = fmaf(wv.z, fs[j], acc[j].z);
                acc[j].w = fmaf(wv.w, fs[j], acc[j].w);
            }
        }

        #pragma unroll
        for (int j = 0; j < 8; ++j) {
            const int n = n0 + nn + j;
            const float px = posb[0 * N_ + n];
            const float py = posb[1 * N_ + n];
            const float pz = posb[2 * N_ + n];
            float4 a = acc[j];
            a.w = fmaf(-px, a.x, fmaf(-py, a.y, fmaf(-pz, a.z, a.w)));  // h
            #pragma unroll
            for (int k = 0; k < K_; ++k) {
                const float4 r = recb[(size_t)n * K_ + k];    // contiguous bcast
                const int slot = __float_as_int(r.w);
                const float c  = fmaf(r.x, a.x, fmaf(r.y, a.y, fmaf(r.z, a.z, a.w)));
                cb[((size_t)slot << 6) + lane] = __float2half(c);  // 128 B / wave
            }
        }
    }
}

struct h4 { __half2 lo, hi; };   // 8 B

__global__ __launch_bounds__(512) void fc_gatherA(
    const __half* __restrict__ contrib,
    const int*    __restrict__ offsets,
    const int*    __restrict__ counts,
    const float*  __restrict__ bias,
    float*        __restrict__ out)     // [B, COUT, N]
{
    __shared__ float T[64][65];
    __shared__ float V[64][65];
    const int tid  = threadIdx.x;
    const int lane = tid & 63;
    const int w    = tid >> 6;            // 0..7

    const int tiles_per_b = N_ / 64;      // 256
    const int b  = blockIdx.x / tiles_per_b;
    const int n0 = (blockIdx.x % tiles_per_b) * 64;

    const __half* cb  = contrib + ((size_t)b * EDGES_PER_B << 6);
    const h4*     cb4 = (const h4*)cb;

    for (int g = 0; g < 8; ++g) {
        const int jj = w * 8 + g;
        const int j  = n0 + jj;
        const int base = offsets[b * N_ + j];
        const int cnt  = counts[b * N_ + j];

        // vector part: lane l covers row-offset (l>>4), channels 4*(l&15)+c
        // one row = 64 halves = 16 h4 units
        const h4* p4 = cb4 + ((size_t)base << 4) + (lane >> 4) * 16 + (lane & 15);
        float2 sl = make_float2(0.f, 0.f);
        float2 sh = make_float2(0.f, 0.f);
        const int full = cnt >> 2;          // groups of 4 rows
        int it = 0;
        for (; it + 2 <= full; it += 2) {   // 2 in flight (8 rows)
            const h4 a0 = p4[0];
            const h4 a1 = p4[64];
            float2 t0 = __half22float2(a0.lo), t1 = __half22float2(a1.lo);
            sl.x += t0.x + t1.x; sl.y += t0.y + t1.y;
            t0 = __half22float2(a0.hi); t1 = __half22float2(a1.hi);
            sh.x += t0.x + t1.x; sh.y += t0.y + t1.y;
            p4 += 128;
        }
        if (it < full) {
            const h4 a0 = p4[0];
            float2 t0 = __half22float2(a0.lo);
            sl.x += t0.x; sl.y += t0.y;
            t0 = __half22float2(a0.hi);
            sh.x += t0.x; sh.y += t0.y;
        }
        // reduce the 4 lanes sharing each channel set (l, l+16, l+32, l+48)
        sl.x += __shfl_xor(sl.x, 16); sl.y += __shfl_xor(sl.y, 16);
        sh.x += __shfl_xor(sh.x, 16); sh.y += __shfl_xor(sh.y, 16);
        sl.x += __shfl_xor(sl.x, 32); sl.y += __shfl_xor(sl.y, 32);
        sh.x += __shfl_xor(sh.x, 32); sh.y += __shfl_xor(sh.y, 32);

        // scalar tail rows
        float tail = 0.f;
        const __half* pt = cb + (((size_t)(base + (full << 2))) << 6) + lane;
        for (int e = full << 2; e < cnt; ++e) { tail += __half2float(*pt); pt += 64; }

        T[jj][lane] = tail;
        if (lane < 16) {
            V[jj][4 * lane + 0] = sl.x;
            V[jj][4 * lane + 1] = sl.y;
            V[jj][4 * lane + 2] = sh.x;
            V[jj][4 * lane + 3] = sh.y;
        }
    }
    __syncthreads();

    float* outb = out + (size_t)b * COUT_ * N_;
    for (int r = 0; r < 8; ++r) {
        const int o = r * 8 + w;
        outb[(size_t)o * N_ + n0 + lane] = T[lane][o] + V[lane][o] + bias[o];
    }
}

// ===========================================================================
// PATH A-OLD (~131 MiB ws): round-2 verified fp32 pipeline (fallback).
// ===========================================================================

__global__ __launch_bounds__(256) void fc_fill_slot(
    const int* __restrict__ nbh,
    int*       __restrict__ cursor,
    int*       __restrict__ slotmap)
{
    const int gid = blockIdx.x * 256 + threadIdx.x;
    const int b   = gid / EDGES_PER_B;
    const int j   = nbh[gid];
    slotmap[gid] = atomicAdd(&cursor[b * N_ + j], 1);
}

__global__ __launch_bounds__(256) void fc_contrib(
    const float* __restrict__ feat,
    const float* __restrict__ theta,
    const float* __restrict__ wbias,
    const int*   __restrict__ nbh,
    const int*   __restrict__ slotmap,
    const float* __restrict__ pos,
    float*       __restrict__ contrib)
{
    __shared__ float4 Wl[CIN_ * COUT_];
    __shared__ float  Fl[CIN_ * 64];

    const int tid  = threadIdx.x;
    const int lane = tid & 63;
    const int w    = tid >> 6;

    const int blocks_per_b = N_ / 128;
    const int b     = blockIdx.x / blocks_per_b;
    const int nbase = (blockIdx.x % blocks_per_b) * 128;

    for (int e = tid; e < CIN_ * COUT_; e += 256) {
        const int i = e >> 6, o = e & 63;
        float4 wv;
        wv.x = theta[0 * CIN_ * COUT_ + i * COUT_ + o];
        wv.y = theta[1 * CIN_ * COUT_ + i * COUT_ + o];
        wv.z = theta[2 * CIN_ * COUT_ + i * COUT_ + o];
        wv.w = wbias[i * COUT_ + o];
        Wl[e] = wv;
    }

    const float* featb = feat + (size_t)b * CIN_ * N_;
    const float* posb  = pos  + (size_t)b * 3 * N_;
    const int*   nbhb  = nbh  + (size_t)b * K_ * N_;
    const int*   smb   = slotmap + (size_t)b * EDGES_PER_B;
    float*       cb    = contrib + ((size_t)b * EDGES_PER_B << 6);

    for (int t = 0; t < 2; ++t) {
        const int n0 = nbase + t * 64;

        __syncthreads();
        for (int r = 0; r < 16; ++r) {
            const int i = r * 4 + w;
            Fl[i * 64 + lane] = featb[(size_t)i * N_ + n0 + lane];
        }
        __syncthreads();

        for (int g = 0; g < 4; ++g) {
            const int nn = w * 16 + g * 4;
            float4 acc[4];
            #pragma unroll
            for (int j = 0; j < 4; ++j) acc[j] = make_float4(0.f, 0.f, 0.f, 0.f);

            #pragma unroll 8
            for (int i = 0; i < CIN_; ++i) {
                const float4 wv = Wl[i * 64 + lane];
                const float f0 = Fl[i * 64 + nn + 0];
                const float f1 = Fl[i * 64 + nn + 1];
                const float f2 = Fl[i * 64 + nn + 2];
                const float f3 = Fl[i * 64 + nn + 3];
                acc[0].x = fmaf(wv.x, f0, acc[0].x);
                acc[0].y = fmaf(wv.y, f0, acc[0].y);
                acc[0].z = fmaf(wv.z, f0, acc[0].z);
                acc[0].w = fmaf(wv.w, f0, acc[0].w);
                acc[1].x = fmaf(wv.x, f1, acc[1].x);
                acc[1].y = fmaf(wv.y, f1, acc[1].y);
                acc[1].z = fmaf(wv.z, f1, acc[1].z);
                acc[1].w = fmaf(wv.w, f1, acc[1].w);
                acc[2].x = fmaf(wv.x, f2, acc[2].x);
                acc[2].y = fmaf(wv.y, f2, acc[2].y);
                acc[2].z = fmaf(wv.z, f2, acc[2].z);
                acc[2].w = fmaf(wv.w, f2, acc[2].w);
                acc[3].x = fmaf(wv.x, f3, acc[3].x);
                acc[3].y = fmaf(wv.y, f3, acc[3].y);
                acc[3].z = fmaf(wv.z, f3, acc[3].z);
                acc[3].w = fmaf(wv.w, f3, acc[3].w);
            }

            #pragma unroll
            for (int j = 0; j < 4; ++j) {
                const int n = n0 + nn + j;
                const float px = posb[0 * N_ + n];
                const float py = posb[1 * N_ + n];
                const float pz = posb[2 * N_ + n];
                float4 a = acc[j];
                a.w = fmaf(-px, a.x, fmaf(-py, a.y, fmaf(-pz, a.z, a.w)));
                #pragma unroll
                for (int k = 0; k < K_; ++k) {
                    const int jt   = nbhb[k * N_ + n];
                    const int slot = smb[k * N_ + n];
                    const float qx = posb[0 * N_ + jt];
                    const float qy = posb[1 * N_ + jt];
                    const float qz = posb[2 * N_ + jt];
                    const float c  = fmaf(qx, a.x, fmaf(qy, a.y, fmaf(qz, a.z, a.w)));
                    cb[((size_t)slot << 6) + lane] = c;
                }
            }
        }
    }
}

__global__ __launch_bounds__(512) void fc_gather3(
    const float* __restrict__ contrib,
    const int*   __restrict__ offsets,
    const int*   __restrict__ counts,
    const float* __restrict__ bias,
    float*       __restrict__ out)
{
    __shared__ float T[64][65];
    const int tid  = threadIdx.x;
    const int lane = tid & 63;
    const int w    = tid >> 6;

    const int tiles_per_b = N_ / 64;
    const int b  = blockIdx.x / tiles_per_b;
    const int n0 = (blockIdx.x % tiles_per_b) * 64;

    const float* cb = contrib + ((size_t)b * EDGES_PER_B << 6);

    for (int g = 0; g < 8; ++g) {
        const int jj = w * 8 + g;
        const int j  = n0 + jj;
        const int base = offsets[b * N_ + j];
        const int cnt  = counts[b * N_ + j];

        const float* p = cb + ((size_t)base << 6) + lane;
        float acc = 0.f;
        int e = 0;
        for (; e + 4 <= cnt; e += 4) {
            const float v0 = p[0];
            const float v1 = p[64];
            const float v2 = p[128];
            const float v3 = p[192];
            acc += (v0 + v1) + (v2 + v3);
            p += 256;
        }
        for (; e < cnt; ++e) { acc += *p; p += 64; }
        T[jj][lane] = acc;
    }
    __syncthreads();

    float* outb = out + (size_t)b * COUT_ * N_;
    for (int r = 0; r < 8; ++r) {
        const int o = r * 8 + w;
        outb[(size_t)o * N_ + n0 + lane] = T[lane][o] + bias[o];
    }
}

// ===========================================================================
// PATH C (16 MiB ws): verified atomic-scatter fallback.
// ===========================================================================
__global__ __launch_bounds__(256) void flexconv_main(
    const float* __restrict__ feat,
    const float* __restrict__ theta,
    const float* __restrict__ wbias,
    const int*   __restrict__ nbh,
    const float* __restrict__ pos,
    float*       __restrict__ ws)
{
    __shared__ float4 Wl[CIN_ * COUT_];
    __shared__ float  Fl[CIN_ * 64];

    const int tid  = threadIdx.x;
    const int lane = tid & 63;
    const int w    = tid >> 6;

    const int blocks_per_b = N_ / 128;
    const int b     = blockIdx.x / blocks_per_b;
    const int nbase = (blockIdx.x % blocks_per_b) * 128;

    for (int e = tid; e < CIN_ * COUT_; e += 256) {
        const int i = e >> 6, o = e & 63;
        float4 wv;
        wv.x = theta[0 * CIN_ * COUT_ + i * COUT_ + o];
        wv.y = theta[1 * CIN_ * COUT_ + i * COUT_ + o];
        wv.z = theta[2 * CIN_ * COUT_ + i * COUT_ + o];
        wv.w = wbias[i * COUT_ + o];
        Wl[e] = wv;
    }

    const float* featb = feat + (size_t)b * CIN_ * N_;
    const float* posb  = pos  + (size_t)b * 3 * N_;
    const int*   nbhb  = nbh  + (size_t)b * K_ * N_;
    float*       wsb   = ws   + (size_t)b * N_ * COUT_;

    for (int t = 0; t < 2; ++t) {
        const int n0 = nbase + t * 64;

        __syncthreads();
        for (int r = 0; r < 16; ++r) {
            const int i = r * 4 + w;
            Fl[i * 64 + lane] = featb[(size_t)i * N_ + n0 + lane];
        }
        __syncthreads();

        for (int g = 0; g < 4; ++g) {
            const int nn = w * 16 + g * 4;
            float4 acc[4];
            #pragma unroll
            for (int j = 0; j < 4; ++j) acc[j] = make_float4(0.f, 0.f, 0.f, 0.f);

            #pragma unroll 8
            for (int i = 0; i < CIN_; ++i) {
                const float4 wv = Wl[i * 64 + lane];
                const float f0 = Fl[i * 64 + nn + 0];
                const float f1 = Fl[i * 64 + nn + 1];
                const float f2 = Fl[i * 64 + nn + 2];
                const float f3 = Fl[i * 64 + nn + 3];
                acc[0].x = fmaf(wv.x, f0, acc[0].x);
                acc[0].y = fmaf(wv.y, f0, acc[0].y);
                acc[0].z = fmaf(wv.z, f0, acc[0].z);
                acc[0].w = fmaf(wv.w, f0, acc[0].w);
                acc[1].x = fmaf(wv.x, f1, acc[1].x);
                acc[1].y = fmaf(wv.y, f1, acc[1].y);
                acc[1].z = fmaf(wv.z, f1, acc[1].z);
                acc[1].w = fmaf(wv.w, f1, acc[1].w);
                acc[2].x = fmaf(wv.x, f2, acc[2].x);
                acc[2].y = fmaf(wv.y, f2, acc[2].y);
                acc[2].z = fmaf(wv.z, f2, acc[2].z);
                acc[2].w = fmaf(wv.w, f2, acc[2].w);
                acc[3].x = fmaf(wv.x, f3, acc[3].x);
                acc[3].y = fmaf(wv.y, f3, acc[3].y);
                acc[3].z = fmaf(wv.z, f3, acc[3].z);
                acc[3].w = fmaf(wv.w, f3, acc[3].w);
            }

            #pragma unroll
            for (int j = 0; j < 4; ++j) {
                const int n = n0 + nn + j;
                const float px = posb[0 * N_ + n];
                const float py = posb[1 * N_ + n];
                const float pz = posb[2 * N_ + n];
                const float4 a = acc[j];
                #pragma unroll
                for (int k = 0; k < K_; ++k) {
                    const int idx = nbhb[k * N_ + n];
                    const float dx = posb[0 * N_ + idx] - px;
                    const float dy = posb[1 * N_ + idx] - py;
                    const float dz = posb[2 * N_ + idx] - pz;
                    const float c  = fmaf(dx, a.x, fmaf(dy, a.y, fmaf(dz, a.z, a.w)));
                    atomicAdd(&wsb[(size_t)idx * COUT_ + lane], c);
                }
            }
        }
    }
}

__global__ __launch_bounds__(256) void flexconv_finish(
    const float* __restrict__ ws,
    const float* __restrict__ bias,
    float*       __restrict__ out)
{
    __shared__ float T[64][65];
    const int tid  = threadIdx.x;
    const int lane = tid & 63;
    const int w    = tid >> 6;

    const int tiles_per_b = N_ / 64;
    const int b  = blockIdx.x / tiles_per_b;
    const int n0 = (blockIdx.x % tiles_per_b) * 64;

    const float* wsb = ws + (size_t)b * N_ * COUT_;
    for (int r = 0; r < 16; ++r) {
        const int nn = r * 4 + w;
        T[nn][lane] = wsb[(size_t)(n0 + nn) * COUT_ + lane];
    }
    __syncthreads();

    float* outb = out + (size_t)b * COUT_ * N_;
    for (int r = 0; r < 16; ++r) {
        const int o = r * 4 + w;
        outb[(size_t)o * N_ + n0 + lane] = T[lane][o] + bias[o];
    }
}

// ===========================================================================
extern "C" void kernel_launch(void* const* d_in, const int* in_sizes, int n_in,
                              void* d_out, int out_size, void* d_ws, size_t ws_size,
                              hipStream_t stream) {
    const float* features = (const float*)d_in[0];
    const float* theta    = (const float*)d_in[1];
    const float* wbias    = (const float*)d_in[2];
    const int*   nbh      = (const int*)  d_in[3];
    const float* pos      = (const float*)d_in[4];
    const float* bias     = (const float*)d_in[5];
    float* out = (float*)d_out;

    const size_t counts_bytes    = (size_t)B_ * N_ * sizeof(int);            // 256 KiB
    const size_t map_bytes       = (size_t)TOT_EDGES * sizeof(int);          // 2 MiB
    const size_t rec_bytes       = (size_t)TOT_EDGES * sizeof(float4);       // 8 MiB
    const size_t contribh_bytes  = (size_t)TOT_EDGES * COUT_ * sizeof(__half); // 64 MiB
    const size_t contribf_bytes  = (size_t)TOT_EDGES * COUT_ * sizeof(float);  // 128 MiB

    // ---- Path A: fp16 contrib + offsets + counts + cursor + rec (~73 MiB) ----
    {
        size_t off = 0;
        __half* contrib = (__half*)((char*)d_ws + off); off += contribh_bytes;
        int*    offsets = (int*)   ((char*)d_ws + off); off += counts_bytes;
        int*    counts  = (int*)   ((char*)d_ws + off); off += counts_bytes;
        int*    cursor  = (int*)   ((char*)d_ws + off); off += counts_bytes;
        float4* rec     = (float4*)((char*)d_ws + off); off += rec_bytes;

        if (ws_size >= off) {
            hipMemsetAsync(counts, 0, counts_bytes, stream);
            fc_hist<<<TOT_EDGES / 256, 256, 0, stream>>>(nbh, counts);
            fc_scan<<<B_, 256, 0, stream>>>(counts, offsets, cursor);
            fc_rec<<<(B_ * N_) / 256, 256, 0, stream>>>(nbh, pos, cursor, rec);
            fc_contribA<<<B_ * (N_ / 128), 512, 0, stream>>>(features, theta, wbias,
                                                             rec, pos, contrib);
            fc_gatherA<<<B_ * (N_ / 64), 512, 0, stream>>>(contrib, offsets, counts,
                                                           bias, out);
            return;
        }
    }

    // ---- Path A-old: round-2 fp32 pipeline (~131 MiB) ----
    {
        size_t off = 0;
        float* contrib = (float*)((char*)d_ws + off); off += contribf_bytes;
        int* counts  = (int*)((char*)d_ws + off); off += counts_bytes;
        int* offsets = (int*)((char*)d_ws + off); off += counts_bytes;
        int* cursor  = (int*)((char*)d_ws + off); off += counts_bytes;
        int* slotmap = (int*)((char*)d_ws + off); off += map_bytes;

        if (ws_size >= off) {
            hipMemsetAsync(counts, 0, counts_bytes, stream);
            fc_hist<<<TOT_EDGES / 256, 256, 0, stream>>>(nbh, counts);
            fc_scan<<<B_, 256, 0, stream>>>(counts, offsets, cursor);
            fc_fill_slot<<<TOT_EDGES / 256, 256, 0, stream>>>(nbh, cursor, slotmap);
            fc_contrib<<<B_ * (N_ / 128), 256, 0, stream>>>(features, theta, wbias,
                                                            nbh, slotmap, pos, contrib);
            fc_gather3<<<B_ * (N_ / 64), 512, 0, stream>>>(contrib, offsets, counts,
                                                           bias, out);
            return;
        }
    }

    // ---- Path C: atomic fallback (16 MiB) ----
    {
        float* ws = (float*)d_ws;
        const size_t ws_bytes = (size_t)B_ * N_ * COUT_ * sizeof(float);
        hipMemsetAsync(ws, 0, ws_bytes, stream);
        flexconv_main<<<B_ * (N_ / 128), 256, 0, stream>>>(features, theta, wbias,
                                                           nbh, pos, ws);
        flexconv_finish<<<B_ * (N_ / 64), 256, 0, stream>>>(ws, bias, out);
    }
}